// Round 3
// baseline (192.636 us; speedup 1.0000x reference)
//
#include <hip/hip_runtime.h>

// LTCN layer R3: zero-barrier main kernel.
// Pre-kernel permutes+converts all weights to bf16 B-fragment order in d_ws.
// Main kernel: one WG = (block j, 64 batch rows); A-operands global->reg,
// B-fragments global->reg (L2-hot); nets round-trip through WAVE-PRIVATE LDS
// rows (no __syncthreads anywhere); biases/tau computed per-lane.

#define IN_DIM 256
#define K 64
#define NB 64
#define BATCH 4096
#define NTOT 4096
#define DTC 0.05f
#define TAU_EPS 1e-6f
#define NSTR 72                 // net LDS row stride (bf16)

// ws layout (bf16 elems); each 64x64 block = 4096 elems in B-fragment order
#define WS_WREC 0
#define WS_EL   (64 * 4096)
#define WS_ELR  (128 * 4096)
#define WS_WFWD (192 * 4096)    // 63 blocks (j-1 = 0..62)
#define WS_WIN  (255 * 4096)    // 4 k-chunks of W_in
#define WS_BLOCKS 259

typedef __bf16 bf16;
typedef bf16 bf16x8 __attribute__((ext_vector_type(8)));
typedef float f32x4 __attribute__((ext_vector_type(4)));

__device__ __forceinline__ float fast_tanh(float x) {
    float e = __expf(2.0f * x);
    return 1.0f - 2.0f * __builtin_amdgcn_rcpf(e + 1.0f);
}

// fragment chunk index: ((kh*4+ct)*64 + l16*4 + quad) * 8 elems
__device__ __forceinline__ bf16x8 bfrag(const bf16* __restrict__ base,
                                        int kh, int ct, int lofs) {
    return *(const bf16x8*)(base + ((((kh * 4 + ct) << 6) + lofs) << 3));
}

// Load one 64-wide A row slice into two bf16x8 fragments (k 0..31, 32..63).
__device__ __forceinline__ void load_afrag(const float* __restrict__ rowp,
                                           bf16x8& f0, bf16x8& f1) {
    float4 a0 = *(const float4*)(rowp);
    float4 a1 = *(const float4*)(rowp + 4);
    float4 a2 = *(const float4*)(rowp + 32);
    float4 a3 = *(const float4*)(rowp + 36);
    f0 = (bf16x8){ (bf16)a0.x, (bf16)a0.y, (bf16)a0.z, (bf16)a0.w,
                   (bf16)a1.x, (bf16)a1.y, (bf16)a1.z, (bf16)a1.w };
    f1 = (bf16x8){ (bf16)a2.x, (bf16)a2.y, (bf16)a2.z, (bf16)a2.w,
                   (bf16)a3.x, (bf16)a3.y, (bf16)a3.z, (bf16)a3.w };
}

// ---- Pre-kernel: f32 weights -> bf16 fragment-ordered ws ----
__global__ __launch_bounds__(256)
void perm_weights(const float* __restrict__ W_in_w, const float* __restrict__ W_fwd_w,
                  const float* __restrict__ W_rec_w, const float* __restrict__ E_l,
                  const float* __restrict__ E_l_r, bf16* __restrict__ wsb) {
    const int g = blockIdx.x;
    const float* src;
    int stride;
    if (g < 64)       { src = W_rec_w + (size_t)g * 4096;         stride = 64;  }
    else if (g < 128) { src = E_l     + (size_t)(g - 64) * 4096;  stride = 64;  }
    else if (g < 192) { src = E_l_r   + (size_t)(g - 128) * 4096; stride = 64;  }
    else if (g < 255) { src = W_fwd_w + (size_t)(g - 192) * 4096; stride = 64;  }
    else              { src = W_in_w + (g - 255) * 64;            stride = 256; }
    bf16* dst = wsb + (size_t)g * 4096;
    const int tid = threadIdx.x;
#pragma unroll
    for (int h = 0; h < 2; ++h) {
        int c = tid * 2 + h;                       // chunk 0..511
        int kh = c >> 8, ct = (c >> 6) & 3, l16 = (c >> 2) & 15, quad = c & 3;
        const float* s = src + (ct * 16 + l16) * stride + kh * 32 + quad * 8;
        float4 a = *(const float4*)s;
        float4 b = *(const float4*)(s + 4);
        bf16x8 p = { (bf16)a.x, (bf16)a.y, (bf16)a.z, (bf16)a.w,
                     (bf16)b.x, (bf16)b.y, (bf16)b.z, (bf16)b.w };
        *(bf16x8*)(dst + (size_t)c * 8) = p;
    }
}

// ---- Main kernel ----
__global__ __launch_bounds__(256, 6)
void ltcn_main(const float* __restrict__ y, const float* __restrict__ u_t,
               const float* __restrict__ tau_raw,
               const float* __restrict__ W_in_b, const float* __restrict__ W_fwd_b,
               const float* __restrict__ W_rec_b,
               const bf16* __restrict__ wsb, float* __restrict__ out) {
    __shared__ bf16 sNO[64 * NSTR];   // wave-private 16-row slices
    __shared__ bf16 sNR[64 * NSTR];

    const int tid  = threadIdx.x;
    const int j    = blockIdx.y;
    const int b0   = blockIdx.x * 64;
    const int wave = tid >> 6;
    const int lane = tid & 63;
    const int quad = lane >> 4;
    const int l16  = lane & 15;
    const int am   = wave * 16 + l16;       // A-fragment row
    const int lofs = l16 * 4 + quad;        // B-fragment chunk offset

    // per-lane biases + inv(tau): no shared arrays, no barrier
    float bfv[4], brv[4], itv[4];
#pragma unroll
    for (int ct = 0; ct < 4; ++ct) {
        int n = ct * 16 + l16;
        brv[ct] = W_rec_b[j * K + n];
        bfv[ct] = j ? W_fwd_b[(j - 1) * K + n] : W_in_b[n];
        float x = tau_raw[j * K + n];
        float sp = (x > 15.0f) ? x : log1pf(__expf(x));
        itv[ct] = 1.0f / (sp + TAU_EPS);
    }

    // ---- rec GEMM ----
    f32x4 accF[4] = {}, accR[4] = {};
    {
        bf16x8 yc0, yc1;
        load_afrag(y + (size_t)(b0 + am) * NTOT + j * K + quad * 8, yc0, yc1);
        const bf16* Wr = wsb + WS_WREC + (size_t)j * 4096;
#pragma unroll
        for (int ct = 0; ct < 4; ++ct) {
            accR[ct] = __builtin_amdgcn_mfma_f32_16x16x32_bf16(yc0, bfrag(Wr, 0, ct, lofs), accR[ct], 0, 0, 0);
            accR[ct] = __builtin_amdgcn_mfma_f32_16x16x32_bf16(yc1, bfrag(Wr, 1, ct, lofs), accR[ct], 0, 0, 0);
        }
    }
    // ---- fwd / input GEMM ----
    if (j) {
        bf16x8 yp0, yp1;
        load_afrag(y + (size_t)(b0 + am) * NTOT + (j - 1) * K + quad * 8, yp0, yp1);
        const bf16* Wf = wsb + WS_WFWD + (size_t)(j - 1) * 4096;
#pragma unroll
        for (int ct = 0; ct < 4; ++ct) {
            accF[ct] = __builtin_amdgcn_mfma_f32_16x16x32_bf16(yp0, bfrag(Wf, 0, ct, lofs), accF[ct], 0, 0, 0);
            accF[ct] = __builtin_amdgcn_mfma_f32_16x16x32_bf16(yp1, bfrag(Wf, 1, ct, lofs), accF[ct], 0, 0, 0);
        }
    } else {
        for (int kc = 0; kc < 4; ++kc) {
            bf16x8 u0, u1;
            load_afrag(u_t + (size_t)(b0 + am) * IN_DIM + kc * 64 + quad * 8, u0, u1);
            const bf16* Wf = wsb + WS_WIN + (size_t)kc * 4096;
#pragma unroll
            for (int ct = 0; ct < 4; ++ct) {
                accF[ct] = __builtin_amdgcn_mfma_f32_16x16x32_bf16(u0, bfrag(Wf, 0, ct, lofs), accF[ct], 0, 0, 0);
                accF[ct] = __builtin_amdgcn_mfma_f32_16x16x32_bf16(u1, bfrag(Wf, 1, ct, lofs), accF[ct], 0, 0, 0);
            }
        }
    }

    // ---- tanh + decay terms + wave-private net round-trip ----
    float absum[4][4];
#pragma unroll
    for (int ct = 0; ct < 4; ++ct) {
#pragma unroll
        for (int r = 0; r < 4; ++r) {
            float no = fast_tanh(accF[ct][r] + bfv[ct]);
            float nr = fast_tanh(accR[ct][r] + brv[ct]);
            absum[ct][r] = fabsf(no) + fabsf(nr);
            int m = wave * 16 + quad * 4 + r;   // row within this wave's slice
            int n = ct * 16 + l16;
            sNO[m * NSTR + n] = (bf16)no;
            sNR[m * NSTR + n] = (bf16)nr;
        }
    }
    // same-wave DS ops are in-order; reads below only touch this wave's rows
    bf16x8 aO0 = *(const bf16x8*)(sNO + am * NSTR + quad * 8);
    bf16x8 aO1 = *(const bf16x8*)(sNO + am * NSTR + quad * 8 + 32);
    bf16x8 aR0 = *(const bf16x8*)(sNR + am * NSTR + quad * 8);
    bf16x8 aR1 = *(const bf16x8*)(sNR + am * NSTR + quad * 8 + 32);

    // ---- drive GEMM ----
    f32x4 accD[4] = {};
    const bf16* El  = wsb + WS_EL  + (size_t)j * 4096;
    const bf16* Elr = wsb + WS_ELR + (size_t)j * 4096;
#pragma unroll
    for (int ct = 0; ct < 4; ++ct) {
        accD[ct] = __builtin_amdgcn_mfma_f32_16x16x32_bf16(aO0, bfrag(El,  0, ct, lofs), accD[ct], 0, 0, 0);
        accD[ct] = __builtin_amdgcn_mfma_f32_16x16x32_bf16(aO1, bfrag(El,  1, ct, lofs), accD[ct], 0, 0, 0);
        accD[ct] = __builtin_amdgcn_mfma_f32_16x16x32_bf16(aR0, bfrag(Elr, 0, ct, lofs), accD[ct], 0, 0, 0);
        accD[ct] = __builtin_amdgcn_mfma_f32_16x16x32_bf16(aR1, bfrag(Elr, 1, ct, lofs), accD[ct], 0, 0, 0);
    }

    // ---- epilogue ----
#pragma unroll
    for (int ct = 0; ct < 4; ++ct) {
#pragma unroll
        for (int r = 0; r < 4; ++r) {
            size_t gi = (size_t)(b0 + wave * 16 + quad * 4 + r) * NTOT + j * K + ct * 16 + l16;
            float decay = itv[ct] + absum[ct][r];
            out[gi] = (y[gi] + DTC * accD[ct][r]) * __builtin_amdgcn_rcpf(1.0f + DTC * decay);
        }
    }
}

extern "C" void kernel_launch(void* const* d_in, const int* in_sizes, int n_in,
                              void* d_out, int out_size, void* d_ws, size_t ws_size,
                              hipStream_t stream) {
    const float* y       = (const float*)d_in[0];
    const float* u_t     = (const float*)d_in[1];
    const float* tau_raw = (const float*)d_in[2];
    const float* W_in_w  = (const float*)d_in[3];
    const float* W_in_b  = (const float*)d_in[4];
    const float* W_fwd_w = (const float*)d_in[5];
    const float* W_fwd_b = (const float*)d_in[6];
    const float* W_rec_w = (const float*)d_in[7];
    const float* W_rec_b = (const float*)d_in[8];
    const float* E_l     = (const float*)d_in[9];
    const float* E_l_r   = (const float*)d_in[10];
    float* out = (float*)d_out;
    bf16* wsb = (bf16*)d_ws;   // needs 259*4096*2 B = 2.12 MB

    hipLaunchKernelGGL(perm_weights, dim3(WS_BLOCKS), dim3(256), 0, stream,
                       W_in_w, W_fwd_w, W_rec_w, E_l, E_l_r, wsb);
    hipLaunchKernelGGL(ltcn_main, dim3(BATCH / 64, NB), dim3(256), 0, stream,
                       y, u_t, tau_raw, W_in_b, W_fwd_b, W_rec_b, wsb, out);
}

// Round 4
// 174.349 us; speedup vs baseline: 1.1049x; 1.1049x over previous
//
#include <hip/hip_runtime.h>

// LTCN R4: zero-barrier, ILP-restored.
// Pre-kernel permutes weights to bf16 B-fragment order in d_ws (as R3).
// Main kernel: WG = (block j, 64 batch rows). y-tile staged wave-privately
// into f32 LDS (A-frags + epilogue both read it). B-fragments loaded
// global->reg in explicit 8-wide batches (one vmcnt drain per phase).
// launch_bounds(256,4): 128-VGPR budget so batches stay in flight.

#define IN_DIM 256
#define K 64
#define NB 64
#define BATCH 4096
#define NTOT 4096
#define DTC 0.05f
#define TAU_EPS 1e-6f
#define NSTR 72                 // net LDS row stride (bf16)
#define YSTR 68                 // y LDS row stride (f32), 16B-aligned rows

// ws layout (bf16 elems); each 64x64 block = 4096 elems in B-fragment order
#define WS_WREC 0
#define WS_EL   (64 * 4096)
#define WS_ELR  (128 * 4096)
#define WS_WFWD (192 * 4096)    // 63 blocks (j-1 = 0..62)
#define WS_WIN  (255 * 4096)    // 4 k-chunks of W_in
#define WS_BLOCKS 259

typedef __bf16 bf16;
typedef bf16 bf16x8 __attribute__((ext_vector_type(8)));
typedef float f32x4 __attribute__((ext_vector_type(4)));

__device__ __forceinline__ float fast_tanh(float x) {
    float e = __expf(2.0f * x);
    return 1.0f - 2.0f * __builtin_amdgcn_rcpf(e + 1.0f);
}

// fragment chunk: ((kh*4+ct)*64 + l16*4 + quad) * 8 elems
__device__ __forceinline__ bf16x8 bfrag(const bf16* __restrict__ base,
                                        int kh, int ct, int lofs) {
    return *(const bf16x8*)(base + ((((kh * 4 + ct) << 6) + lofs) << 3));
}

__device__ __forceinline__ void load_afrag(const float* __restrict__ rowp,
                                           bf16x8& f0, bf16x8& f1) {
    float4 a0 = *(const float4*)(rowp);
    float4 a1 = *(const float4*)(rowp + 4);
    float4 a2 = *(const float4*)(rowp + 32);
    float4 a3 = *(const float4*)(rowp + 36);
    f0 = (bf16x8){ (bf16)a0.x, (bf16)a0.y, (bf16)a0.z, (bf16)a0.w,
                   (bf16)a1.x, (bf16)a1.y, (bf16)a1.z, (bf16)a1.w };
    f1 = (bf16x8){ (bf16)a2.x, (bf16)a2.y, (bf16)a2.z, (bf16)a2.w,
                   (bf16)a3.x, (bf16)a3.y, (bf16)a3.z, (bf16)a3.w };
}

// ---- Pre-kernel: f32 weights -> bf16 fragment-ordered ws ----
__global__ __launch_bounds__(256)
void perm_weights(const float* __restrict__ W_in_w, const float* __restrict__ W_fwd_w,
                  const float* __restrict__ W_rec_w, const float* __restrict__ E_l,
                  const float* __restrict__ E_l_r, bf16* __restrict__ wsb) {
    const int g = blockIdx.x;
    const float* src;
    int stride;
    if (g < 64)       { src = W_rec_w + (size_t)g * 4096;         stride = 64;  }
    else if (g < 128) { src = E_l     + (size_t)(g - 64) * 4096;  stride = 64;  }
    else if (g < 192) { src = E_l_r   + (size_t)(g - 128) * 4096; stride = 64;  }
    else if (g < 255) { src = W_fwd_w + (size_t)(g - 192) * 4096; stride = 64;  }
    else              { src = W_in_w + (g - 255) * 64;            stride = 256; }
    bf16* dst = wsb + (size_t)g * 4096;
    const int tid = threadIdx.x;
#pragma unroll
    for (int h = 0; h < 2; ++h) {
        int c = tid * 2 + h;                       // chunk 0..511
        int kh = c >> 8, ct = (c >> 6) & 3, l16 = (c >> 2) & 15, quad = c & 3;
        const float* s = src + (ct * 16 + l16) * stride + kh * 32 + quad * 8;
        float4 a = *(const float4*)s;
        float4 b = *(const float4*)(s + 4);
        bf16x8 p = { (bf16)a.x, (bf16)a.y, (bf16)a.z, (bf16)a.w,
                     (bf16)b.x, (bf16)b.y, (bf16)b.z, (bf16)b.w };
        *(bf16x8*)(dst + (size_t)c * 8) = p;
    }
}

// ---- Main kernel ----
__global__ __launch_bounds__(256, 4)
void ltcn_main(const float* __restrict__ y, const float* __restrict__ u_t,
               const float* __restrict__ tau_raw,
               const float* __restrict__ W_in_b, const float* __restrict__ W_fwd_b,
               const float* __restrict__ W_rec_b,
               const bf16* __restrict__ wsb, float* __restrict__ out) {
    __shared__ float sY [64 * YSTR];  // y tile, f32, wave-private 16-row slices
    __shared__ bf16  sNO[64 * NSTR];  // nets, wave-private
    __shared__ bf16  sNR[64 * NSTR];

    const int tid  = threadIdx.x;
    const int j    = blockIdx.y;
    const int b0   = blockIdx.x * 64;
    const int wave = tid >> 6;
    const int lane = tid & 63;
    const int quad = lane >> 4;
    const int l16  = lane & 15;
    const int am   = wave * 16 + l16;       // A-fragment row
    const int lofs = l16 * 4 + quad;        // B-fragment chunk offset

    // ---- stage own 16 y rows into LDS (f32), coalesced 64B/lane ----
    {
        int r  = lane >> 2;
        int cb = (lane & 3) * 16;
        const float* ysrc = y + (size_t)(b0 + wave * 16 + r) * NTOT + j * K + cb;
        float* ydst = sY + (wave * 16 + r) * YSTR + cb;
#pragma unroll
        for (int i = 0; i < 4; ++i)
            *(float4*)(ydst + i * 4) = *(const float4*)(ysrc + i * 4);
    }

    // per-lane biases + inv(tau)
    float bfv[4], brv[4], itv[4];
#pragma unroll
    for (int ct = 0; ct < 4; ++ct) {
        int n = ct * 16 + l16;
        brv[ct] = W_rec_b[j * K + n];
        bfv[ct] = j ? W_fwd_b[(j - 1) * K + n] : W_in_b[n];
        float x = tau_raw[j * K + n];
        float sp = (x > 15.0f) ? x : log1pf(__expf(x));
        itv[ct] = 1.0f / (sp + TAU_EPS);
    }

    // ---- y_cur A-frags from LDS (wave-private rows) ----
    bf16x8 yc0, yc1;
    {
        const float* p = sY + am * YSTR + quad * 8;
        float4 a0 = *(const float4*)(p);
        float4 a1 = *(const float4*)(p + 4);
        float4 a2 = *(const float4*)(p + 32);
        float4 a3 = *(const float4*)(p + 36);
        yc0 = (bf16x8){ (bf16)a0.x, (bf16)a0.y, (bf16)a0.z, (bf16)a0.w,
                        (bf16)a1.x, (bf16)a1.y, (bf16)a1.z, (bf16)a1.w };
        yc1 = (bf16x8){ (bf16)a2.x, (bf16)a2.y, (bf16)a2.z, (bf16)a2.w,
                        (bf16)a3.x, (bf16)a3.y, (bf16)a3.z, (bf16)a3.w };
    }

    // ---- rec GEMM: batched B loads (8 frags in flight) ----
    f32x4 accF[4] = {}, accR[4] = {};
    {
        const bf16* Wr = wsb + WS_WREC + (size_t)j * 4096;
        bf16x8 wr[8];
#pragma unroll
        for (int t = 0; t < 8; ++t) wr[t] = bfrag(Wr, t >> 2, t & 3, lofs);
#pragma unroll
        for (int ct = 0; ct < 4; ++ct) {
            accR[ct] = __builtin_amdgcn_mfma_f32_16x16x32_bf16(yc0, wr[ct],     accR[ct], 0, 0, 0);
            accR[ct] = __builtin_amdgcn_mfma_f32_16x16x32_bf16(yc1, wr[4 + ct], accR[ct], 0, 0, 0);
        }
    }
    // ---- fwd / input GEMM ----
    if (j) {
        bf16x8 yp0, yp1;
        load_afrag(y + (size_t)(b0 + am) * NTOT + (j - 1) * K + quad * 8, yp0, yp1);
        const bf16* Wf = wsb + WS_WFWD + (size_t)(j - 1) * 4096;
        bf16x8 wf[8];
#pragma unroll
        for (int t = 0; t < 8; ++t) wf[t] = bfrag(Wf, t >> 2, t & 3, lofs);
#pragma unroll
        for (int ct = 0; ct < 4; ++ct) {
            accF[ct] = __builtin_amdgcn_mfma_f32_16x16x32_bf16(yp0, wf[ct],     accF[ct], 0, 0, 0);
            accF[ct] = __builtin_amdgcn_mfma_f32_16x16x32_bf16(yp1, wf[4 + ct], accF[ct], 0, 0, 0);
        }
    } else {
        for (int kc = 0; kc < 4; ++kc) {
            bf16x8 u0, u1;
            load_afrag(u_t + (size_t)(b0 + am) * IN_DIM + kc * 64 + quad * 8, u0, u1);
            const bf16* Wf = wsb + WS_WIN + (size_t)kc * 4096;
            bf16x8 wf[8];
#pragma unroll
            for (int t = 0; t < 8; ++t) wf[t] = bfrag(Wf, t >> 2, t & 3, lofs);
#pragma unroll
            for (int ct = 0; ct < 4; ++ct) {
                accF[ct] = __builtin_amdgcn_mfma_f32_16x16x32_bf16(u0, wf[ct],     accF[ct], 0, 0, 0);
                accF[ct] = __builtin_amdgcn_mfma_f32_16x16x32_bf16(u1, wf[4 + ct], accF[ct], 0, 0, 0);
            }
        }
    }

    // ---- tanh + denominator + wave-private net round-trip ----
    float den[4][4];
#pragma unroll
    for (int ct = 0; ct < 4; ++ct) {
#pragma unroll
        for (int r = 0; r < 4; ++r) {
            float no = fast_tanh(accF[ct][r] + bfv[ct]);
            float nr = fast_tanh(accR[ct][r] + brv[ct]);
            den[ct][r] = 1.0f + DTC * (itv[ct] + fabsf(no) + fabsf(nr));
            int m = wave * 16 + quad * 4 + r;
            int n = ct * 16 + l16;
            sNO[m * NSTR + n] = (bf16)no;
            sNR[m * NSTR + n] = (bf16)nr;
        }
    }
    // same-wave DS in-order; reads touch only this wave's rows
    bf16x8 aO0 = *(const bf16x8*)(sNO + am * NSTR + quad * 8);
    bf16x8 aO1 = *(const bf16x8*)(sNO + am * NSTR + quad * 8 + 32);
    bf16x8 aR0 = *(const bf16x8*)(sNR + am * NSTR + quad * 8);
    bf16x8 aR1 = *(const bf16x8*)(sNR + am * NSTR + quad * 8 + 32);

    // ---- drive GEMM: two 8-wide B batches ----
    f32x4 accD[4] = {};
    {
        const bf16* El = wsb + WS_EL + (size_t)j * 4096;
        bf16x8 el[8];
#pragma unroll
        for (int t = 0; t < 8; ++t) el[t] = bfrag(El, t >> 2, t & 3, lofs);
#pragma unroll
        for (int ct = 0; ct < 4; ++ct) {
            accD[ct] = __builtin_amdgcn_mfma_f32_16x16x32_bf16(aO0, el[ct],     accD[ct], 0, 0, 0);
            accD[ct] = __builtin_amdgcn_mfma_f32_16x16x32_bf16(aO1, el[4 + ct], accD[ct], 0, 0, 0);
        }
    }
    {
        const bf16* Elr = wsb + WS_ELR + (size_t)j * 4096;
        bf16x8 er[8];
#pragma unroll
        for (int t = 0; t < 8; ++t) er[t] = bfrag(Elr, t >> 2, t & 3, lofs);
#pragma unroll
        for (int ct = 0; ct < 4; ++ct) {
            accD[ct] = __builtin_amdgcn_mfma_f32_16x16x32_bf16(aR0, er[ct],     accD[ct], 0, 0, 0);
            accD[ct] = __builtin_amdgcn_mfma_f32_16x16x32_bf16(aR1, er[4 + ct], accD[ct], 0, 0, 0);
        }
    }

    // ---- epilogue: y from LDS (wave-private rows), coalesced stores ----
#pragma unroll
    for (int ct = 0; ct < 4; ++ct) {
#pragma unroll
        for (int r = 0; r < 4; ++r) {
            int m = wave * 16 + quad * 4 + r;
            float yv = sY[m * YSTR + ct * 16 + l16];
            size_t gi = (size_t)(b0 + m) * NTOT + j * K + ct * 16 + l16;
            out[gi] = (yv + DTC * accD[ct][r]) * __builtin_amdgcn_rcpf(den[ct][r]);
        }
    }
}

extern "C" void kernel_launch(void* const* d_in, const int* in_sizes, int n_in,
                              void* d_out, int out_size, void* d_ws, size_t ws_size,
                              hipStream_t stream) {
    const float* y       = (const float*)d_in[0];
    const float* u_t     = (const float*)d_in[1];
    const float* tau_raw = (const float*)d_in[2];
    const float* W_in_w  = (const float*)d_in[3];
    const float* W_in_b  = (const float*)d_in[4];
    const float* W_fwd_w = (const float*)d_in[5];
    const float* W_fwd_b = (const float*)d_in[6];
    const float* W_rec_w = (const float*)d_in[7];
    const float* W_rec_b = (const float*)d_in[8];
    const float* E_l     = (const float*)d_in[9];
    const float* E_l_r   = (const float*)d_in[10];
    float* out = (float*)d_out;
    bf16* wsb = (bf16*)d_ws;   // 259*4096*2 B = 2.12 MB

    hipLaunchKernelGGL(perm_weights, dim3(WS_BLOCKS), dim3(256), 0, stream,
                       W_in_w, W_fwd_w, W_rec_w, E_l, E_l_r, wsb);
    hipLaunchKernelGGL(ltcn_main, dim3(BATCH / 64, NB), dim3(256), 0, stream,
                       y, u_t, tau_raw, W_in_b, W_fwd_b, W_rec_b, wsb, out);
}